// Round 2
// baseline (14883.932 us; speedup 1.0000x reference)
//
#include <hip/hip_runtime.h>

#define DEV static __device__ __forceinline__

typedef _Float16 half8  __attribute__((ext_vector_type(8)));
typedef _Float16 half4v __attribute__((ext_vector_type(4)));
typedef float    floatx4 __attribute__((ext_vector_type(4)));
typedef unsigned int u32;
typedef unsigned long long u64;

// Split scale: lo = f16((v - f16(v)) * 1024); combine = hi + lo/1024.
// Keeps residuals in f16 normal range (unscaled W residuals ~4e-6 are subnormal).
#define SPLIT_S 1024.0f
#define SPLIT_R (1.0f / 1024.0f)

// async global->LDS, 16B/lane: LDS dest wave-uniform base + lane*16.
DEV void gl_lds16(const _Float16* g, _Float16* l) {
  __builtin_amdgcn_global_load_lds(
      (const __attribute__((address_space(1))) u32*)g,
      (__attribute__((address_space(3))) u32*)l, 16, 0, 0);
}

// ---------------------------------------------------------------------------
// Convert W_out->f16; init h_pub buf0 = split(h0); zero flags.
__global__ __launch_bounds__(256) void k_convert(
    const float* __restrict__ wout, const float* __restrict__ h0,
    _Float16* __restrict__ WoutF, _Float16* __restrict__ hpub,
    int* __restrict__ flags)
{
  if (blockIdx.x == 0 && threadIdx.x < 128) flags[threadIdx.x] = 0;
  const int NW4 = (2048 * 2048) / 4;
  for (int i = blockIdx.x * 256 + threadIdx.x; i < NW4; i += gridDim.x * 256) {
    const float4 v = ((const float4*)wout)[i];
    half4v o;
    o[0] = (_Float16)v.x; o[1] = (_Float16)v.y;
    o[2] = (_Float16)v.z; o[3] = (_Float16)v.w;
    ((half4v*)WoutF)[i] = o;
  }
  for (int i = blockIdx.x * 256 + threadIdx.x; i < 8 * 2048; i += gridDim.x * 256) {
    const float v = h0[i];
    const _Float16 hi = (_Float16)v;
    hpub[i]          = hi;                                   // [buf0][hi]
    hpub[16384 + i]  = (_Float16)((v - (float)hi) * SPLIT_S); // [buf0][lo]
  }
}

// ---------------------------------------------------------------------------
// Split-f16 GEMM: C[m,n] = sum_k A[m,k]*B[n,k], A/B fp32 row-major (MxK, NxK).
// 128x128 tile, BK=32, 4 waves 2x2, reg-staged with on-the-fly hi/lo split.
// EPI 0: C = silu(v) fp32.  EPI 1: C[(t*8+b)*N+n] = v + bias[n] fp32.
template <int EPI>
__global__ __launch_bounds__(256) void k_gemm_split(
    const float* __restrict__ A, const float* __restrict__ B,
    float* __restrict__ C, const float* __restrict__ bias,
    int M, int N, int K)
{
  __shared__ _Float16 Ah[4096], Al[4096], Bh[4096], Bl[4096];
  const int tid  = threadIdx.x;
  const int lane = tid & 63, wave = tid >> 6;
  const int wm = wave >> 1, wn = wave & 1;
  const int tm = blockIdx.y * 128, tn = blockIdx.x * 128;
  const int lr = lane & 15, lk = lane >> 4;

  floatx4 acch[4][4] = {};
  floatx4 accl[4][4] = {};

  for (int k0 = 0; k0 < K; k0 += 32) {
    float4 av[4], bv[4];
#pragma unroll
    for (int q = 0; q < 4; ++q) {
      const int c = tid + q * 256;           // chunk 0..1023 (float4 units)
      const int rr = c >> 3, cc = (c & 7) * 4;
      av[q] = *(const float4*)(A + (size_t)(tm + rr) * K + k0 + cc);
      bv[q] = *(const float4*)(B + (size_t)(tn + rr) * K + k0 + cc);
    }
    __syncthreads();   // previous iteration's frag reads complete
#pragma unroll
    for (int q = 0; q < 4; ++q) {
      const int c = tid + q * 256;
      const int rr = c >> 3, cc = (c & 7) * 4;
      half4v ah, al, bh, bl;
#pragma unroll
      for (int j = 0; j < 4; ++j) {
        const float xa = av[q][j], xb = bv[q][j];
        const _Float16 ha = (_Float16)xa, hb = (_Float16)xb;
        ah[j] = ha; al[j] = (_Float16)((xa - (float)ha) * SPLIT_S);
        bh[j] = hb; bl[j] = (_Float16)((xb - (float)hb) * SPLIT_S);
      }
      *(half4v*)(Ah + rr * 32 + cc) = ah;
      *(half4v*)(Al + rr * 32 + cc) = al;
      *(half4v*)(Bh + rr * 32 + cc) = bh;
      *(half4v*)(Bl + rr * 32 + cc) = bl;
    }
    __syncthreads();

    half8 fah[4], fal[4], fbh[4], fbl[4];
#pragma unroll
    for (int mi = 0; mi < 4; ++mi) {
      const int off = (wm * 64 + mi * 16 + lr) * 32 + lk * 8;
      fah[mi] = *(const half8*)(Ah + off);
      fal[mi] = *(const half8*)(Al + off);
    }
#pragma unroll
    for (int ni = 0; ni < 4; ++ni) {
      const int off = (wn * 64 + ni * 16 + lr) * 32 + lk * 8;
      fbh[ni] = *(const half8*)(Bh + off);
      fbl[ni] = *(const half8*)(Bl + off);
    }
#pragma unroll
    for (int mi = 0; mi < 4; ++mi)
#pragma unroll
      for (int ni = 0; ni < 4; ++ni) {
        acch[mi][ni] = __builtin_amdgcn_mfma_f32_16x16x32_f16(fah[mi], fbh[ni], acch[mi][ni], 0, 0, 0);
        accl[mi][ni] = __builtin_amdgcn_mfma_f32_16x16x32_f16(
            fah[mi], fbl[ni],
            __builtin_amdgcn_mfma_f32_16x16x32_f16(fal[mi], fbh[ni], accl[mi][ni], 0, 0, 0),
            0, 0, 0);
      }
  }

#pragma unroll
  for (int mi = 0; mi < 4; ++mi)
#pragma unroll
    for (int ni = 0; ni < 4; ++ni) {
      const int gcol = tn + wn * 64 + ni * 16 + lr;
#pragma unroll
      for (int r = 0; r < 4; ++r) {
        const int grow = tm + wm * 64 + mi * 16 + lk * 4 + r;
        const float v = acch[mi][ni][r] + accl[mi][ni][r] * SPLIT_R;
        if (EPI == 0) {
          C[(size_t)grow * N + gcol] = v / (1.0f + expf(-v));
        } else {
          const int tt = grow & 1023, bb = grow >> 10;
          C[(size_t)(tt * 8 + bb) * N + gcol] = v + bias[gcol];
        }
      }
    }
}

// ---------------------------------------------------------------------------
// Plain-f16 GEMM for y = (outs/8) . Wout^T, epilogue *8 (errors don't feed back).
__global__ __launch_bounds__(256) void k_gemm_out(
    const _Float16* __restrict__ A, const _Float16* __restrict__ B,
    float* __restrict__ C, int M, int N, int K)
{
  __shared__ _Float16 As[4096];
  __shared__ _Float16 Bs[4096];
  const int tid  = threadIdx.x;
  const int lane = tid & 63, wave = tid >> 6;
  const int wm = wave >> 1, wn = wave & 1;
  const int tm = blockIdx.y * 128, tn = blockIdx.x * 128;
  const int lr = lane & 15, lk = lane >> 4;
  const int r0 = tid >> 2;
  const int c0 = (tid & 3) * 8;

  floatx4 acc[4][4] = {};

  for (int k0 = 0; k0 < K; k0 += 32) {
#pragma unroll
    for (int c = 0; c < 2; ++c) {
      const int row = c * 64 + r0;
      gl_lds16(A + (size_t)(tm + row) * K + k0 + c0, As + c * 2048 + wave * 512);
      gl_lds16(B + (size_t)(tn + row) * K + k0 + c0, Bs + c * 2048 + wave * 512);
    }
    __syncthreads();

    half8 af[4], bf[4];
#pragma unroll
    for (int mi = 0; mi < 4; ++mi)
      af[mi] = *(const half8*)(As + (wm * 64 + mi * 16 + lr) * 32 + lk * 8);
#pragma unroll
    for (int ni = 0; ni < 4; ++ni)
      bf[ni] = *(const half8*)(Bs + (wn * 64 + ni * 16 + lr) * 32 + lk * 8);
#pragma unroll
    for (int mi = 0; mi < 4; ++mi)
#pragma unroll
      for (int ni = 0; ni < 4; ++ni)
        acc[mi][ni] = __builtin_amdgcn_mfma_f32_16x16x32_f16(af[mi], bf[ni], acc[mi][ni], 0, 0, 0);
    __syncthreads();
  }

#pragma unroll
  for (int mi = 0; mi < 4; ++mi)
#pragma unroll
    for (int ni = 0; ni < 4; ++ni) {
      const int gcol = tn + wn * 64 + ni * 16 + lr;
#pragma unroll
      for (int r = 0; r < 4; ++r) {
        const int grow = tm + wm * 64 + mi * 16 + lk * 4 + r;
        C[(size_t)grow * N + gcol] = acc[mi][ni][r] * 8.0f;
      }
    }
}

// ---------------------------------------------------------------------------
// Persistent recurrence, split-f16. 128 WGs x 256 thr; WG g owns cols e0=g*16.
// Wave w holds W_h[e0..+16)[w*512..+512) as hi/lo f16 frags (128 VGPRs).
// h published per step as f16 hi/lo pairs: hpub[buf][part][b][d] (f16),
// buf stride 32768, part stride 16384 halves. flags[g]=t => WG g published t.
__global__ __launch_bounds__(256) void k_recur(
    const float* __restrict__ Wh, const float* __restrict__ wxp,
    const float* __restrict__ h0p, const float* __restrict__ lalpha,
    _Float16* __restrict__ outs, _Float16* h_pub, int* flags)
{
  __shared__ float red[4 * 64 * 4];
  const int tid = threadIdx.x;
  const int lane = tid & 63, wave = tid >> 6;
  const int g = blockIdx.x;
  const int e0 = g * 16;
  const int lr = lane & 15, lk = lane >> 4;
  const float alpha = expf(lalpha[0]);

  // Preload + split W_h fragments (fp32 global -> hi/lo f16 regs), once.
  half8 afh[16], afl[16];
#pragma unroll
  for (int ks = 0; ks < 16; ++ks) {
    const float* wp = Wh + (size_t)(e0 + lr) * 2048 + wave * 512 + ks * 32 + lk * 8;
    const float4 f0 = *(const float4*)wp;
    const float4 f1 = *(const float4*)(wp + 4);
    half8 h, l;
#pragma unroll
    for (int j = 0; j < 4; ++j) {
      const _Float16 h0_ = (_Float16)f0[j];
      const _Float16 h1_ = (_Float16)f1[j];
      h[j]     = h0_; l[j]     = (_Float16)((f0[j] - (float)h0_) * SPLIT_S);
      h[j + 4] = h1_; l[j + 4] = (_Float16)((f1[j] - (float)h1_) * SPLIT_S);
    }
    afh[ks] = h; afl[ks] = l;
  }

  float hr0 = 0.f, hr1 = 0.f, hr2 = 0.f, hr3 = 0.f;
  if (tid < 64 && (lane & 15) < 8) {
    const float4 hv = *(const float4*)(h0p + (size_t)(lane & 15) * 2048 + e0 + (lane >> 4) * 4);
    hr0 = hv.x; hr1 = hv.y; hr2 = hv.z; hr3 = hv.w;
  }

  for (int t = 0; t < 1024; ++t) {
    if (t > 0) {
      const int j = tid & 127;
      while (__hip_atomic_load(flags + j, __ATOMIC_RELAXED, __HIP_MEMORY_SCOPE_AGENT) < t)
        __builtin_amdgcn_s_sleep(2);
      __builtin_amdgcn_fence(__ATOMIC_ACQUIRE, "agent");  // inv L2 -> fresh h
    }
    __syncthreads();

    // Partial pre = W_slice . h over this wave's K range, split-f16 3-pass.
    const _Float16* hb = h_pub + (size_t)(t & 1) * 32768;
    floatx4 ph[4] = {};
    floatx4 pl[4] = {};
#pragma unroll
    for (int ks = 0; ks < 16; ++ks) {
      const int k = wave * 512 + ks * 32 + lk * 8;
      half8 bh = {}, bl = {};
      if (lr < 8) {
        bh = *(const half8*)(hb + (size_t)lr * 2048 + k);
        bl = *(const half8*)(hb + 16384 + (size_t)lr * 2048 + k);
      }
      ph[ks & 3] = __builtin_amdgcn_mfma_f32_16x16x32_f16(afh[ks], bh, ph[ks & 3], 0, 0, 0);
      pl[ks & 3] = __builtin_amdgcn_mfma_f32_16x16x32_f16(
          afh[ks], bl,
          __builtin_amdgcn_mfma_f32_16x16x32_f16(afl[ks], bh, pl[ks & 3], 0, 0, 0),
          0, 0, 0);
    }
    const floatx4 pt = (ph[0] + ph[1] + ph[2] + ph[3]) +
                       (pl[0] + pl[1] + pl[2] + pl[3]) * SPLIT_R;
    *(floatx4*)&red[(wave * 64 + lane) * 4] = pt;
    __syncthreads();

    if (tid < 64) {
      const floatx4* R = (const floatx4*)red;
      const floatx4 s = R[lane] + R[64 + lane] + R[128 + lane] + R[192 + lane];
      const int b = lane & 15, eg = lane >> 4;
      if (b < 8) {
        const float4 wv = *(const float4*)(wxp + (size_t)(t * 8 + b) * 2048 + e0 + eg * 4);
        hr0 += alpha * tanhf(s[0] + wv.x);
        hr1 += alpha * tanhf(s[1] + wv.y);
        hr2 += alpha * tanhf(s[2] + wv.z);
        hr3 += alpha * tanhf(s[3] + wv.w);
        union { _Float16 h[4]; u64 u; } ov, hv, lv;
        ov.h[0] = (_Float16)((hr0 * hr0 / (1.f + expf(-hr0))) * 0.125f);
        ov.h[1] = (_Float16)((hr1 * hr1 / (1.f + expf(-hr1))) * 0.125f);
        ov.h[2] = (_Float16)((hr2 * hr2 / (1.f + expf(-hr2))) * 0.125f);
        ov.h[3] = (_Float16)((hr3 * hr3 / (1.f + expf(-hr3))) * 0.125f);
        hv.h[0] = (_Float16)hr0; hv.h[1] = (_Float16)hr1;
        hv.h[2] = (_Float16)hr2; hv.h[3] = (_Float16)hr3;
        lv.h[0] = (_Float16)((hr0 - (float)hv.h[0]) * SPLIT_S);
        lv.h[1] = (_Float16)((hr1 - (float)hv.h[1]) * SPLIT_S);
        lv.h[2] = (_Float16)((hr2 - (float)hv.h[2]) * SPLIT_S);
        lv.h[3] = (_Float16)((hr3 - (float)hv.h[3]) * SPLIT_S);
        *(u64*)(outs + (size_t)(b * 1024 + t) * 2048 + e0 + eg * 4) = ov.u;
        _Float16* dst = h_pub + (size_t)((t + 1) & 1) * 32768 + (size_t)b * 2048 + e0 + eg * 4;
        __hip_atomic_store((u64*)dst,           hv.u, __ATOMIC_RELAXED, __HIP_MEMORY_SCOPE_AGENT);
        __hip_atomic_store((u64*)(dst + 16384), lv.u, __ATOMIC_RELAXED, __HIP_MEMORY_SCOPE_AGENT);
      }
    }
    __syncthreads();   // drains vmcnt -> publish stores complete
    if (tid == 0) {
      __builtin_amdgcn_fence(__ATOMIC_RELEASE, "agent");  // wbl2 -> LLC
      __hip_atomic_store(flags + g, t + 1, __ATOMIC_RELAXED, __HIP_MEMORY_SCOPE_AGENT);
    }
  }
}

// ---------------------------------------------------------------------------
extern "C" void kernel_launch(void* const* d_in, const int* in_sizes, int n_in,
                              void* d_out, int out_size, void* d_ws, size_t ws_size,
                              hipStream_t stream)
{
  (void)in_sizes; (void)n_in; (void)out_size; (void)ws_size;
  const float* x    = (const float*)d_in[0];
  const float* h0   = (const float*)d_in[1];
  const float* Win  = (const float*)d_in[2];
  const float* Wx   = (const float*)d_in[3];
  const float* Wh   = (const float*)d_in[4];
  const float* bias = (const float*)d_in[5];
  const float* lal  = (const float*)d_in[6];
  const float* Wout = (const float*)d_in[7];

  char* ws = (char*)d_ws;
  float*    U     = (float*)(ws);                    // 67,108,864 B (fp32 u)
  _Float16* OUTS  = (_Float16*)(ws);                 // aliases U (U dead after GEMM2)
  _Float16* WoutF = (_Float16*)(ws + 67108864);      //  8,388,608 B
  _Float16* hpub  = (_Float16*)(ws + 75497472);      //    131,072 B [2][2][8][2048] f16
  int*      flags = (int*)     (ws + 75628544);      //        512 B
  float*    wxbuf = (float*)d_out;                   // wx staged in d_out

  const dim3 gg(16, 64);  // N/128, M/128

  k_convert<<<512, 256, 0, stream>>>(Wout, h0, WoutF, hpub, flags);
  // u = silu(x . W_in^T)  (split-f16, fp32 out)
  k_gemm_split<0><<<gg, 256, 0, stream>>>(x, Win, U, nullptr, 8192, 2048, 2048);
  // wx[t][b][:] = u . W_x^T + b  (split-f16, fp32 out in d_out)
  k_gemm_split<1><<<gg, 256, 0, stream>>>(U, Wx, wxbuf, bias, 8192, 2048, 2048);
  // sequential scan; writes outs/8 (f16) over the dead U region
  k_recur<<<128, 256, 0, stream>>>(Wh, wxbuf, h0, lal, OUTS, hpub, flags);
  // y = outs . W_out^T  (epilogue *8), overwrites d_out
  k_gemm_out<<<gg, 256, 0, stream>>>(OUTS, WoutF, (float*)d_out, 8192, 2048, 2048);
}

// Round 3
// 10209.212 us; speedup vs baseline: 1.4579x; 1.4579x over previous
//
#include <hip/hip_runtime.h>

#define DEV static __device__ __forceinline__

typedef _Float16 half8  __attribute__((ext_vector_type(8)));
typedef _Float16 half4v __attribute__((ext_vector_type(4)));
typedef float    floatx4 __attribute__((ext_vector_type(4)));
typedef unsigned int u32;
typedef unsigned long long u64;

// Split scale: lo = f16((v - f16(v)) * 1024); combine = hi + lo/1024.
#define SPLIT_S 1024.0f
#define SPLIT_R (1.0f / 1024.0f)

// async global->LDS, 16B/lane: LDS dest wave-uniform base + lane*16.
DEV void gl_lds16(const _Float16* g, _Float16* l) {
  __builtin_amdgcn_global_load_lds(
      (const __attribute__((address_space(1))) u32*)g,
      (__attribute__((address_space(3))) u32*)l, 16, 0, 0);
}

// Overflow-safe fast tanh: tanh(x) = sign(x) * (1 - 2/(1+e^{2|x|})).
// e^{2|x|} -> +inf for large |x| gives exactly 1.0 (no NaN).
DEV float fast_tanh(float x) {
  const float e = __expf(2.0f * fabsf(x));
  return copysignf(1.0f - 2.0f / (1.0f + e), x);
}

// ---------------------------------------------------------------------------
// Convert W_out->f16; init h_pub buf0 = split(h0); zero flags.
__global__ __launch_bounds__(256) void k_convert(
    const float* __restrict__ wout, const float* __restrict__ h0,
    _Float16* __restrict__ WoutF, _Float16* __restrict__ hpub,
    int* __restrict__ flags)
{
  if (blockIdx.x == 0 && threadIdx.x < 128) flags[threadIdx.x] = 0;
  const int NW4 = (2048 * 2048) / 4;
  for (int i = blockIdx.x * 256 + threadIdx.x; i < NW4; i += gridDim.x * 256) {
    const float4 v = ((const float4*)wout)[i];
    half4v o;
    o[0] = (_Float16)v.x; o[1] = (_Float16)v.y;
    o[2] = (_Float16)v.z; o[3] = (_Float16)v.w;
    ((half4v*)WoutF)[i] = o;
  }
  for (int i = blockIdx.x * 256 + threadIdx.x; i < 8 * 2048; i += gridDim.x * 256) {
    const float v = h0[i];
    const _Float16 hi = (_Float16)v;
    hpub[i]          = hi;                                    // [buf0][hi]
    hpub[16384 + i]  = (_Float16)((v - (float)hi) * SPLIT_S); // [buf0][lo]
  }
}

// ---------------------------------------------------------------------------
// Split-f16 GEMM: C[m,n] = sum_k A[m,k]*B[n,k], A/B fp32 row-major (MxK, NxK).
// 128x128 tile, BK=32, 4 waves 2x2, reg-staged with on-the-fly hi/lo split.
// EPI 0: C = silu(v) fp32.  EPI 1: C[(t*8+b)*N+n] = v + bias[n] fp32.
template <int EPI>
__global__ __launch_bounds__(256) void k_gemm_split(
    const float* __restrict__ A, const float* __restrict__ B,
    float* __restrict__ C, const float* __restrict__ bias,
    int M, int N, int K)
{
  __shared__ _Float16 Ah[4096], Al[4096], Bh[4096], Bl[4096];
  const int tid  = threadIdx.x;
  const int lane = tid & 63, wave = tid >> 6;
  const int wm = wave >> 1, wn = wave & 1;
  const int tm = blockIdx.y * 128, tn = blockIdx.x * 128;
  const int lr = lane & 15, lk = lane >> 4;

  floatx4 acch[4][4] = {};
  floatx4 accl[4][4] = {};

  for (int k0 = 0; k0 < K; k0 += 32) {
    float4 av[4], bv[4];
#pragma unroll
    for (int q = 0; q < 4; ++q) {
      const int c = tid + q * 256;           // chunk 0..1023 (float4 units)
      const int rr = c >> 3, cc = (c & 7) * 4;
      av[q] = *(const float4*)(A + (size_t)(tm + rr) * K + k0 + cc);
      bv[q] = *(const float4*)(B + (size_t)(tn + rr) * K + k0 + cc);
    }
    __syncthreads();   // previous iteration's frag reads complete
#pragma unroll
    for (int q = 0; q < 4; ++q) {
      const int c = tid + q * 256;
      const int rr = c >> 3, cc = (c & 7) * 4;
      half4v ah, al, bh, bl;
#pragma unroll
      for (int j = 0; j < 4; ++j) {
        const float xa = av[q][j], xb = bv[q][j];
        const _Float16 ha = (_Float16)xa, hb = (_Float16)xb;
        ah[j] = ha; al[j] = (_Float16)((xa - (float)ha) * SPLIT_S);
        bh[j] = hb; bl[j] = (_Float16)((xb - (float)hb) * SPLIT_S);
      }
      *(half4v*)(Ah + rr * 32 + cc) = ah;
      *(half4v*)(Al + rr * 32 + cc) = al;
      *(half4v*)(Bh + rr * 32 + cc) = bh;
      *(half4v*)(Bl + rr * 32 + cc) = bl;
    }
    __syncthreads();

    half8 fah[4], fal[4], fbh[4], fbl[4];
#pragma unroll
    for (int mi = 0; mi < 4; ++mi) {
      const int off = (wm * 64 + mi * 16 + lr) * 32 + lk * 8;
      fah[mi] = *(const half8*)(Ah + off);
      fal[mi] = *(const half8*)(Al + off);
    }
#pragma unroll
    for (int ni = 0; ni < 4; ++ni) {
      const int off = (wn * 64 + ni * 16 + lr) * 32 + lk * 8;
      fbh[ni] = *(const half8*)(Bh + off);
      fbl[ni] = *(const half8*)(Bl + off);
    }
#pragma unroll
    for (int mi = 0; mi < 4; ++mi)
#pragma unroll
      for (int ni = 0; ni < 4; ++ni) {
        acch[mi][ni] = __builtin_amdgcn_mfma_f32_16x16x32_f16(fah[mi], fbh[ni], acch[mi][ni], 0, 0, 0);
        accl[mi][ni] = __builtin_amdgcn_mfma_f32_16x16x32_f16(
            fah[mi], fbl[ni],
            __builtin_amdgcn_mfma_f32_16x16x32_f16(fal[mi], fbh[ni], accl[mi][ni], 0, 0, 0),
            0, 0, 0);
      }
  }

#pragma unroll
  for (int mi = 0; mi < 4; ++mi)
#pragma unroll
    for (int ni = 0; ni < 4; ++ni) {
      const int gcol = tn + wn * 64 + ni * 16 + lr;
#pragma unroll
      for (int r = 0; r < 4; ++r) {
        const int grow = tm + wm * 64 + mi * 16 + lk * 4 + r;
        const float v = acch[mi][ni][r] + accl[mi][ni][r] * SPLIT_R;
        if (EPI == 0) {
          C[(size_t)grow * N + gcol] = v / (1.0f + __expf(-v));
        } else {
          const int tt = grow & 1023, bb = grow >> 10;
          C[(size_t)(tt * 8 + bb) * N + gcol] = v + bias[gcol];
        }
      }
    }
}

// ---------------------------------------------------------------------------
// Plain-f16 GEMM for y = (outs/8) . Wout^T, epilogue *8 (errors don't feed back).
__global__ __launch_bounds__(256) void k_gemm_out(
    const _Float16* __restrict__ A, const _Float16* __restrict__ B,
    float* __restrict__ C, int M, int N, int K)
{
  __shared__ _Float16 As[4096];
  __shared__ _Float16 Bs[4096];
  const int tid  = threadIdx.x;
  const int lane = tid & 63, wave = tid >> 6;
  const int wm = wave >> 1, wn = wave & 1;
  const int tm = blockIdx.y * 128, tn = blockIdx.x * 128;
  const int lr = lane & 15, lk = lane >> 4;
  const int r0 = tid >> 2;
  const int c0 = (tid & 3) * 8;

  floatx4 acc[4][4] = {};

  for (int k0 = 0; k0 < K; k0 += 32) {
#pragma unroll
    for (int c = 0; c < 2; ++c) {
      const int row = c * 64 + r0;
      gl_lds16(A + (size_t)(tm + row) * K + k0 + c0, As + c * 2048 + wave * 512);
      gl_lds16(B + (size_t)(tn + row) * K + k0 + c0, Bs + c * 2048 + wave * 512);
    }
    __syncthreads();

    half8 af[4], bf[4];
#pragma unroll
    for (int mi = 0; mi < 4; ++mi)
      af[mi] = *(const half8*)(As + (wm * 64 + mi * 16 + lr) * 32 + lk * 8);
#pragma unroll
    for (int ni = 0; ni < 4; ++ni)
      bf[ni] = *(const half8*)(Bs + (wn * 64 + ni * 16 + lr) * 32 + lk * 8);
#pragma unroll
    for (int mi = 0; mi < 4; ++mi)
#pragma unroll
      for (int ni = 0; ni < 4; ++ni)
        acc[mi][ni] = __builtin_amdgcn_mfma_f32_16x16x32_f16(af[mi], bf[ni], acc[mi][ni], 0, 0, 0);
    __syncthreads();
  }

#pragma unroll
  for (int mi = 0; mi < 4; ++mi)
#pragma unroll
    for (int ni = 0; ni < 4; ++ni) {
      const int gcol = tn + wn * 64 + ni * 16 + lr;
#pragma unroll
      for (int r = 0; r < 4; ++r) {
        const int grow = tm + wm * 64 + mi * 16 + lk * 4 + r;
        C[(size_t)grow * N + gcol] = acc[mi][ni][r] * 8.0f;
      }
    }
}

// ---------------------------------------------------------------------------
// Persistent recurrence, split-f16, FENCE-FREE protocol.
// All cross-WG data moves through LLC via sc1 (relaxed agent-scope atomic)
// loads/stores; flag ordered behind h stores by raw s_waitcnt vmcnt(0).
// No buffer_inv / buffer_wbl2 anywhere in the loop.
// 128 WGs x 256 thr; WG g owns cols e0=g*16. Wave w holds
// W_h[e0..+16)[w*512..+512) as hi/lo f16 frags in regs (1 WG/CU -> VGPRs free).
__global__ __launch_bounds__(256) void k_recur(
    const float* __restrict__ Wh, const float* __restrict__ wxp,
    const float* __restrict__ h0p, const float* __restrict__ lalpha,
    _Float16* __restrict__ outs, _Float16* h_pub, int* flags)
{
  __shared__ float red[4 * 64 * 4];
  const int tid = threadIdx.x;
  const int lane = tid & 63, wave = tid >> 6;
  const int g = blockIdx.x;
  const int e0 = g * 16;
  const int lr = lane & 15, lk = lane >> 4;
  const float alpha = __expf(lalpha[0]);

  // Preload + split W_h fragments (fp32 global -> hi/lo f16 regs), once.
  half8 afh[16], afl[16];
#pragma unroll
  for (int ks = 0; ks < 16; ++ks) {
    const float* wp = Wh + (size_t)(e0 + lr) * 2048 + wave * 512 + ks * 32 + lk * 8;
    const float4 f0 = *(const float4*)wp;
    const float4 f1 = *(const float4*)(wp + 4);
    half8 h, l;
#pragma unroll
    for (int j = 0; j < 4; ++j) {
      const _Float16 h0_ = (_Float16)f0[j];
      const _Float16 h1_ = (_Float16)f1[j];
      h[j]     = h0_; l[j]     = (_Float16)((f0[j] - (float)h0_) * SPLIT_S);
      h[j + 4] = h1_; l[j + 4] = (_Float16)((f1[j] - (float)h1_) * SPLIT_S);
    }
    afh[ks] = h; afl[ks] = l;
  }

  const bool owner = (tid < 64) && (lr < 8);  // lane b=lr<8 owns batch lr, cols e0+lk*4..+4
  float hr0 = 0.f, hr1 = 0.f, hr2 = 0.f, hr3 = 0.f;
  if (owner) {
    const float4 hv = *(const float4*)(h0p + (size_t)lr * 2048 + e0 + lk * 4);
    hr0 = hv.x; hr1 = hv.y; hr2 = hv.z; hr3 = hv.w;
  }

  for (int t = 0; t < 1024; ++t) {
    // Prefetch wx_t (flag-independent) so its latency hides under the poll.
    float4 wv = {0.f, 0.f, 0.f, 0.f};
    if (owner) wv = *(const float4*)(wxp + (size_t)(t * 8 + lr) * 2048 + e0 + lk * 4);

    // Poll: 128 threads each watch one flag; barrier broadcasts "all >= t".
    if (t > 0 && tid < 128) {
      while (__hip_atomic_load(flags + tid, __ATOMIC_RELAXED, __HIP_MEMORY_SCOPE_AGENT) < t)
        __builtin_amdgcn_s_sleep(1);
    }
    __syncthreads();

    // Partial pre = W_slice . h over this wave's K range, split-f16 3-pass.
    // h read via sc1 atomic u64 loads -> always fresh from LLC, no inv needed.
    const _Float16* hb = h_pub + (size_t)(t & 1) * 32768;
    floatx4 ph[4] = {};
    floatx4 pl[4] = {};
#pragma unroll
    for (int ks = 0; ks < 16; ++ks) {
      const int k = wave * 512 + ks * 32 + lk * 8;
      half8 bh = {}, bl = {};
      if (lr < 8) {
        const u64* p0 = (const u64*)(hb + (size_t)lr * 2048 + k);
        const u64* p1 = (const u64*)(hb + 16384 + (size_t)lr * 2048 + k);
        union { u64 u[2]; half8 h; } ub, uc;
        ub.u[0] = __hip_atomic_load(p0,     __ATOMIC_RELAXED, __HIP_MEMORY_SCOPE_AGENT);
        ub.u[1] = __hip_atomic_load(p0 + 1, __ATOMIC_RELAXED, __HIP_MEMORY_SCOPE_AGENT);
        uc.u[0] = __hip_atomic_load(p1,     __ATOMIC_RELAXED, __HIP_MEMORY_SCOPE_AGENT);
        uc.u[1] = __hip_atomic_load(p1 + 1, __ATOMIC_RELAXED, __HIP_MEMORY_SCOPE_AGENT);
        bh = ub.h; bl = uc.h;
      }
      ph[ks & 3] = __builtin_amdgcn_mfma_f32_16x16x32_f16(afh[ks], bh, ph[ks & 3], 0, 0, 0);
      pl[ks & 3] = __builtin_amdgcn_mfma_f32_16x16x32_f16(
          afh[ks], bl,
          __builtin_amdgcn_mfma_f32_16x16x32_f16(afl[ks], bh, pl[ks & 3], 0, 0, 0),
          0, 0, 0);
    }
    const floatx4 pt = (ph[0] + ph[1] + ph[2] + ph[3]) +
                       (pl[0] + pl[1] + pl[2] + pl[3]) * SPLIT_R;
    *(floatx4*)&red[(wave * 64 + lane) * 4] = pt;
    __syncthreads();

    if (tid < 64) {
      const floatx4* R = (const floatx4*)red;
      const floatx4 s = R[lane] + R[64 + lane] + R[128 + lane] + R[192 + lane];
      union { _Float16 h[4]; u64 u; } hv, lv, ov;
      if (owner) {
        hr0 += alpha * fast_tanh(s[0] + wv.x);
        hr1 += alpha * fast_tanh(s[1] + wv.y);
        hr2 += alpha * fast_tanh(s[2] + wv.z);
        hr3 += alpha * fast_tanh(s[3] + wv.w);
        hv.h[0] = (_Float16)hr0; hv.h[1] = (_Float16)hr1;
        hv.h[2] = (_Float16)hr2; hv.h[3] = (_Float16)hr3;
        lv.h[0] = (_Float16)((hr0 - (float)hv.h[0]) * SPLIT_S);
        lv.h[1] = (_Float16)((hr1 - (float)hv.h[1]) * SPLIT_S);
        lv.h[2] = (_Float16)((hr2 - (float)hv.h[2]) * SPLIT_S);
        lv.h[3] = (_Float16)((hr3 - (float)hv.h[3]) * SPLIT_S);
        _Float16* dst = h_pub + (size_t)((t + 1) & 1) * 32768 + (size_t)lr * 2048 + e0 + lk * 4;
        __hip_atomic_store((u64*)dst,           hv.u, __ATOMIC_RELAXED, __HIP_MEMORY_SCOPE_AGENT);
        __hip_atomic_store((u64*)(dst + 16384), lv.u, __ATOMIC_RELAXED, __HIP_MEMORY_SCOPE_AGENT);
      }
      // Order flag behind the sc1 h-stores (whole wave executes the wait).
      asm volatile("s_waitcnt vmcnt(0)" ::: "memory");
      if (lane == 0)
        __hip_atomic_store(flags + g, t + 1, __ATOMIC_RELAXED, __HIP_MEMORY_SCOPE_AGENT);
      if (owner) {
        // outs is consumed only by the next dispatch -> off the critical path.
        ov.h[0] = (_Float16)((hr0 * hr0 / (1.f + __expf(-hr0))) * 0.125f);
        ov.h[1] = (_Float16)((hr1 * hr1 / (1.f + __expf(-hr1))) * 0.125f);
        ov.h[2] = (_Float16)((hr2 * hr2 / (1.f + __expf(-hr2))) * 0.125f);
        ov.h[3] = (_Float16)((hr3 * hr3 / (1.f + __expf(-hr3))) * 0.125f);
        *(u64*)(outs + (size_t)(lr * 1024 + t) * 2048 + e0 + lk * 4) = ov.u;
      }
    }
    // No trailing barrier needed: a wave can only pass the next poll after
    // this WG's own flag reaches t+1, which wave 0 sets strictly after its
    // red-reads; red writes for t+1 happen after the post-poll barrier.
  }
}

// ---------------------------------------------------------------------------
extern "C" void kernel_launch(void* const* d_in, const int* in_sizes, int n_in,
                              void* d_out, int out_size, void* d_ws, size_t ws_size,
                              hipStream_t stream)
{
  (void)in_sizes; (void)n_in; (void)out_size; (void)ws_size;
  const float* x    = (const float*)d_in[0];
  const float* h0   = (const float*)d_in[1];
  const float* Win  = (const float*)d_in[2];
  const float* Wx   = (const float*)d_in[3];
  const float* Wh   = (const float*)d_in[4];
  const float* bias = (const float*)d_in[5];
  const float* lal  = (const float*)d_in[6];
  const float* Wout = (const float*)d_in[7];

  char* ws = (char*)d_ws;
  float*    U     = (float*)(ws);                    // 67,108,864 B (fp32 u)
  _Float16* OUTS  = (_Float16*)(ws);                 // aliases U (U dead after GEMM2)
  _Float16* WoutF = (_Float16*)(ws + 67108864);      //  8,388,608 B
  _Float16* hpub  = (_Float16*)(ws + 75497472);      //    131,072 B [2][2][8][2048] f16
  int*      flags = (int*)     (ws + 75628544);      //        512 B
  float*    wxbuf = (float*)d_out;                   // wx staged in d_out

  const dim3 gg(16, 64);  // N/128, M/128

  k_convert<<<512, 256, 0, stream>>>(Wout, h0, WoutF, hpub, flags);
  // u = silu(x . W_in^T)  (split-f16, fp32 out)
  k_gemm_split<0><<<gg, 256, 0, stream>>>(x, Win, U, nullptr, 8192, 2048, 2048);
  // wx[t][b][:] = u . W_x^T + b  (split-f16, fp32 out in d_out)
  k_gemm_split<1><<<gg, 256, 0, stream>>>(U, Wx, wxbuf, bias, 8192, 2048, 2048);
  // sequential scan; writes outs/8 (f16) over the dead U region
  k_recur<<<128, 256, 0, stream>>>(Wh, wxbuf, h0, lal, OUTS, hpub, flags);
  // y = outs . W_out^T  (epilogue *8), overwrites d_out
  k_gemm_out<<<gg, 256, 0, stream>>>(OUTS, WoutF, (float*)d_out, 8192, 2048, 2048);
}

// Round 4
// 7161.205 us; speedup vs baseline: 2.0784x; 1.4256x over previous
//
#include <hip/hip_runtime.h>

#define DEV static __device__ __forceinline__

typedef _Float16 half8  __attribute__((ext_vector_type(8)));
typedef _Float16 half4v __attribute__((ext_vector_type(4)));
typedef float    floatx4 __attribute__((ext_vector_type(4)));
typedef unsigned int u32;
typedef unsigned long long u64;

// Split scale: lo = f16((v - f16(v)) * 1024); combine = hi + lo/1024.
#define SPLIT_S 1024.0f
#define SPLIT_R (1.0f / 1024.0f)

// async global->LDS, 16B/lane: LDS dest wave-uniform base + lane*16.
DEV void gl_lds16(const _Float16* g, _Float16* l) {
  __builtin_amdgcn_global_load_lds(
      (const __attribute__((address_space(1))) u32*)g,
      (__attribute__((address_space(3))) u32*)l, 16, 0, 0);
}

// LLC-coherent (bypass L1/L2) pipelined 16B load. NOT atomic -> fully
// overlappable; freshness guaranteed by sc0+sc1 (system scope).
DEV float4 llc_load16(u64 addr) {
  float4 r;
  asm volatile("global_load_dwordx4 %0, %1, off sc0 sc1"
               : "=v"(r) : "v"(addr));
  return r;
}
DEV void llc_store8(u64 addr, u64 v) {
  asm volatile("global_store_dwordx2 %0, %1, off sc0 sc1"
               :: "v"(addr), "v"(v) : "memory");
}
DEV void llc_store4(u64 addr, int v) {
  asm volatile("global_store_dword %0, %1, off sc0 sc1"
               :: "v"(addr), "v"(v) : "memory");
}

// Overflow-safe fast tanh: tanh(x) = sign(x) * (1 - 2/(1+e^{2|x|})).
DEV float fast_tanh(float x) {
  const float e = __expf(2.0f * fabsf(x));
  return copysignf(1.0f - 2.0f / (1.0f + e), x);
}

// ---------------------------------------------------------------------------
// Convert W_out->f16; init h_pub buf0 = split(h0); zero flags.
__global__ __launch_bounds__(256) void k_convert(
    const float* __restrict__ wout, const float* __restrict__ h0,
    _Float16* __restrict__ WoutF, _Float16* __restrict__ hpub,
    int* __restrict__ flags)
{
  if (blockIdx.x == 0 && threadIdx.x < 128) flags[threadIdx.x] = 0;
  const int NW4 = (2048 * 2048) / 4;
  for (int i = blockIdx.x * 256 + threadIdx.x; i < NW4; i += gridDim.x * 256) {
    const float4 v = ((const float4*)wout)[i];
    half4v o;
    o[0] = (_Float16)v.x; o[1] = (_Float16)v.y;
    o[2] = (_Float16)v.z; o[3] = (_Float16)v.w;
    ((half4v*)WoutF)[i] = o;
  }
  for (int i = blockIdx.x * 256 + threadIdx.x; i < 8 * 2048; i += gridDim.x * 256) {
    const float v = h0[i];
    const _Float16 hi = (_Float16)v;
    hpub[i]          = hi;                                    // [buf0][hi]
    hpub[16384 + i]  = (_Float16)((v - (float)hi) * SPLIT_S); // [buf0][lo]
  }
}

// ---------------------------------------------------------------------------
// Split-f16 GEMM: C[m,n] = sum_k A[m,k]*B[n,k], A/B fp32 row-major (MxK, NxK).
// EPI 0: C = silu(v) fp32.  EPI 1: C[(t*8+b)*N+n] = v + bias[n] fp32.
template <int EPI>
__global__ __launch_bounds__(256) void k_gemm_split(
    const float* __restrict__ A, const float* __restrict__ B,
    float* __restrict__ C, const float* __restrict__ bias,
    int M, int N, int K)
{
  __shared__ _Float16 Ah[4096], Al[4096], Bh[4096], Bl[4096];
  const int tid  = threadIdx.x;
  const int lane = tid & 63, wave = tid >> 6;
  const int wm = wave >> 1, wn = wave & 1;
  const int tm = blockIdx.y * 128, tn = blockIdx.x * 128;
  const int lr = lane & 15, lk = lane >> 4;

  floatx4 acch[4][4] = {};
  floatx4 accl[4][4] = {};

  for (int k0 = 0; k0 < K; k0 += 32) {
    float4 av[4], bv[4];
#pragma unroll
    for (int q = 0; q < 4; ++q) {
      const int c = tid + q * 256;           // chunk 0..1023 (float4 units)
      const int rr = c >> 3, cc = (c & 7) * 4;
      av[q] = *(const float4*)(A + (size_t)(tm + rr) * K + k0 + cc);
      bv[q] = *(const float4*)(B + (size_t)(tn + rr) * K + k0 + cc);
    }
    __syncthreads();   // previous iteration's frag reads complete
#pragma unroll
    for (int q = 0; q < 4; ++q) {
      const int c = tid + q * 256;
      const int rr = c >> 3, cc = (c & 7) * 4;
      half4v ah, al, bh, bl;
#pragma unroll
      for (int j = 0; j < 4; ++j) {
        const float xa = av[q][j], xb = bv[q][j];
        const _Float16 ha = (_Float16)xa, hb = (_Float16)xb;
        ah[j] = ha; al[j] = (_Float16)((xa - (float)ha) * SPLIT_S);
        bh[j] = hb; bl[j] = (_Float16)((xb - (float)hb) * SPLIT_S);
      }
      *(half4v*)(Ah + rr * 32 + cc) = ah;
      *(half4v*)(Al + rr * 32 + cc) = al;
      *(half4v*)(Bh + rr * 32 + cc) = bh;
      *(half4v*)(Bl + rr * 32 + cc) = bl;
    }
    __syncthreads();

    half8 fah[4], fal[4], fbh[4], fbl[4];
#pragma unroll
    for (int mi = 0; mi < 4; ++mi) {
      const int off = (wm * 64 + mi * 16 + lr) * 32 + lk * 8;
      fah[mi] = *(const half8*)(Ah + off);
      fal[mi] = *(const half8*)(Al + off);
    }
#pragma unroll
    for (int ni = 0; ni < 4; ++ni) {
      const int off = (wn * 64 + ni * 16 + lr) * 32 + lk * 8;
      fbh[ni] = *(const half8*)(Bh + off);
      fbl[ni] = *(const half8*)(Bl + off);
    }
#pragma unroll
    for (int mi = 0; mi < 4; ++mi)
#pragma unroll
      for (int ni = 0; ni < 4; ++ni) {
        acch[mi][ni] = __builtin_amdgcn_mfma_f32_16x16x32_f16(fah[mi], fbh[ni], acch[mi][ni], 0, 0, 0);
        accl[mi][ni] = __builtin_amdgcn_mfma_f32_16x16x32_f16(
            fah[mi], fbl[ni],
            __builtin_amdgcn_mfma_f32_16x16x32_f16(fal[mi], fbh[ni], accl[mi][ni], 0, 0, 0),
            0, 0, 0);
      }
  }

#pragma unroll
  for (int mi = 0; mi < 4; ++mi)
#pragma unroll
    for (int ni = 0; ni < 4; ++ni) {
      const int gcol = tn + wn * 64 + ni * 16 + lr;
#pragma unroll
      for (int r = 0; r < 4; ++r) {
        const int grow = tm + wm * 64 + mi * 16 + lk * 4 + r;
        const float v = acch[mi][ni][r] + accl[mi][ni][r] * SPLIT_R;
        if (EPI == 0) {
          C[(size_t)grow * N + gcol] = v / (1.0f + __expf(-v));
        } else {
          const int tt = grow & 1023, bb = grow >> 10;
          C[(size_t)(tt * 8 + bb) * N + gcol] = v + bias[gcol];
        }
      }
    }
}

// ---------------------------------------------------------------------------
// Plain-f16 GEMM for y = (outs/8) . Wout^T, epilogue *8.
__global__ __launch_bounds__(256) void k_gemm_out(
    const _Float16* __restrict__ A, const _Float16* __restrict__ B,
    float* __restrict__ C, int M, int N, int K)
{
  __shared__ _Float16 As[4096];
  __shared__ _Float16 Bs[4096];
  const int tid  = threadIdx.x;
  const int lane = tid & 63, wave = tid >> 6;
  const int wm = wave >> 1, wn = wave & 1;
  const int tm = blockIdx.y * 128, tn = blockIdx.x * 128;
  const int lr = lane & 15, lk = lane >> 4;
  const int r0 = tid >> 2;
  const int c0 = (tid & 3) * 8;

  floatx4 acc[4][4] = {};

  for (int k0 = 0; k0 < K; k0 += 32) {
#pragma unroll
    for (int c = 0; c < 2; ++c) {
      const int row = c * 64 + r0;
      gl_lds16(A + (size_t)(tm + row) * K + k0 + c0, As + c * 2048 + wave * 512);
      gl_lds16(B + (size_t)(tn + row) * K + k0 + c0, Bs + c * 2048 + wave * 512);
    }
    __syncthreads();

    half8 af[4], bf[4];
#pragma unroll
    for (int mi = 0; mi < 4; ++mi)
      af[mi] = *(const half8*)(As + (wm * 64 + mi * 16 + lr) * 32 + lk * 8);
#pragma unroll
    for (int ni = 0; ni < 4; ++ni)
      bf[ni] = *(const half8*)(Bs + (wn * 64 + ni * 16 + lr) * 32 + lk * 8);
#pragma unroll
    for (int mi = 0; mi < 4; ++mi)
#pragma unroll
      for (int ni = 0; ni < 4; ++ni)
        acc[mi][ni] = __builtin_amdgcn_mfma_f32_16x16x32_f16(af[mi], bf[ni], acc[mi][ni], 0, 0, 0);
    __syncthreads();
  }

#pragma unroll
  for (int mi = 0; mi < 4; ++mi)
#pragma unroll
    for (int ni = 0; ni < 4; ++ni) {
      const int gcol = tn + wn * 64 + ni * 16 + lr;
#pragma unroll
      for (int r = 0; r < 4; ++r) {
        const int grow = tm + wm * 64 + mi * 16 + lk * 4 + r;
        C[(size_t)grow * N + gcol] = acc[mi][ni][r] * 8.0f;
      }
    }
}

// ---------------------------------------------------------------------------
// Persistent recurrence, split-f16, fence-free, PIPELINED LLC loads.
// 128 WGs x 256 thr (1 WG/CU, 1 wave/SIMD -> up to 512 regs/wave).
// Per step: poll (wave0 only, __all over 128 flags) -> barrier -> issue all
// 32 asm sc0sc1 16B h-loads in flight -> one vmcnt(0) -> 48 MFMA -> LDS
// reduce -> wave0: tanh, publish h (2x8B sc0sc1), vmcnt(0) ack, flag store.
__global__ __launch_bounds__(256, 1) void k_recur(
    const float* __restrict__ Wh, const float* __restrict__ wxp,
    const float* __restrict__ h0p, const float* __restrict__ lalpha,
    _Float16* __restrict__ outs, _Float16* h_pub, int* flags)
{
  __shared__ float red[4 * 64 * 4];
  const int tid = threadIdx.x;
  const int lane = tid & 63, wave = tid >> 6;
  const int g = blockIdx.x;
  const int e0 = g * 16;
  const int lr = lane & 15, lk = lane >> 4;
  const int lrc = lr & 7;   // clamped: lanes lr>=8 duplicate lr-8 (dead B cols)
  const float alpha = __expf(lalpha[0]);

  // Preload + split W_h fragments (fp32 global -> hi/lo f16 regs), once.
  half8 afh[16], afl[16];
#pragma unroll
  for (int ks = 0; ks < 16; ++ks) {
    const float* wp = Wh + (size_t)(e0 + lr) * 2048 + wave * 512 + ks * 32 + lk * 8;
    const float4 f0 = *(const float4*)wp;
    const float4 f1 = *(const float4*)(wp + 4);
    half8 h, l;
#pragma unroll
    for (int j = 0; j < 4; ++j) {
      const _Float16 h0_ = (_Float16)f0[j];
      const _Float16 h1_ = (_Float16)f1[j];
      h[j]     = h0_; l[j]     = (_Float16)((f0[j] - (float)h0_) * SPLIT_S);
      h[j + 4] = h1_; l[j + 4] = (_Float16)((f1[j] - (float)h1_) * SPLIT_S);
    }
    afh[ks] = h; afl[ks] = l;
  }

  const bool owner = (tid < 64) && (lr < 8);  // lane b=lr owns batch lr, cols e0+lk*4..+4
  float hr0 = 0.f, hr1 = 0.f, hr2 = 0.f, hr3 = 0.f;
  if (owner) {
    const float4 hv = *(const float4*)(h0p + (size_t)lr * 2048 + e0 + lk * 4);
    hr0 = hv.x; hr1 = hv.y; hr2 = hv.z; hr3 = hv.w;
  }

  const u64 hpub_base = (u64)h_pub;
  const u64 flag_base = (u64)flags;
  // Per-lane byte offset of this lane's K-slice within a buffer (hi part).
  const u64 lane_off = ((u64)lrc * 2048 + (u64)wave * 512 + (u64)lk * 8) * 2;

  for (int t = 0; t < 1024; ++t) {
    // Prefetch wx_t (flag-independent) so its latency hides under the poll.
    float4 wv = {0.f, 0.f, 0.f, 0.f};
    if (owner) wv = *(const float4*)(wxp + (size_t)(t * 8 + lr) * 2048 + e0 + lk * 4);

    // Poll: wave 0 only; lane watches flags[2*lane], flags[2*lane+1].
    if (t > 0 && wave == 0) {
      const u64* fp = (const u64*)flags + lane;
      for (;;) {
        const u64 fv = __hip_atomic_load(fp, __ATOMIC_RELAXED, __HIP_MEMORY_SCOPE_AGENT);
        if (__all(((int)fv >= t) && ((int)(fv >> 32) >= t))) break;
        __builtin_amdgcn_s_sleep(1);
      }
    }
    __syncthreads();

    // Issue ALL h loads (hi+lo, 16B each) back-to-back -> single wait.
    const u64 lb = hpub_base + (u64)(t & 1) * 65536 + lane_off;
    float4 sh[16], sl[16];
#pragma unroll
    for (int ks = 0; ks < 16; ++ks) {
      sh[ks] = llc_load16(lb + (u64)ks * 64);
      sl[ks] = llc_load16(lb + 32768 + (u64)ks * 64);
    }
    asm volatile("s_waitcnt vmcnt(0)" ::: "memory");
    __builtin_amdgcn_sched_barrier(0);

    floatx4 ph[4] = {};
    floatx4 pl[4] = {};
#pragma unroll
    for (int ks = 0; ks < 16; ++ks) {
      const half8 bh = __builtin_bit_cast(half8, sh[ks]);
      const half8 bl = __builtin_bit_cast(half8, sl[ks]);
      ph[ks & 3] = __builtin_amdgcn_mfma_f32_16x16x32_f16(afh[ks], bh, ph[ks & 3], 0, 0, 0);
      pl[ks & 3] = __builtin_amdgcn_mfma_f32_16x16x32_f16(
          afh[ks], bl,
          __builtin_amdgcn_mfma_f32_16x16x32_f16(afl[ks], bh, pl[ks & 3], 0, 0, 0),
          0, 0, 0);
    }
    const floatx4 pt = (ph[0] + ph[1] + ph[2] + ph[3]) +
                       (pl[0] + pl[1] + pl[2] + pl[3]) * SPLIT_R;
    *(floatx4*)&red[(wave * 64 + lane) * 4] = pt;
    __syncthreads();

    if (tid < 64) {
      const floatx4* R = (const floatx4*)red;
      const floatx4 s = R[lane] + R[64 + lane] + R[128 + lane] + R[192 + lane];
      union { _Float16 h[4]; u64 u; } hv, lv, ov;
      if (owner) {
        hr0 += alpha * fast_tanh(s[0] + wv.x);
        hr1 += alpha * fast_tanh(s[1] + wv.y);
        hr2 += alpha * fast_tanh(s[2] + wv.z);
        hr3 += alpha * fast_tanh(s[3] + wv.w);
        hv.h[0] = (_Float16)hr0; hv.h[1] = (_Float16)hr1;
        hv.h[2] = (_Float16)hr2; hv.h[3] = (_Float16)hr3;
        lv.h[0] = (_Float16)((hr0 - (float)hv.h[0]) * SPLIT_S);
        lv.h[1] = (_Float16)((hr1 - (float)hv.h[1]) * SPLIT_S);
        lv.h[2] = (_Float16)((hr2 - (float)hv.h[2]) * SPLIT_S);
        lv.h[3] = (_Float16)((hr3 - (float)hv.h[3]) * SPLIT_S);
        const u64 dst = hpub_base + (u64)((t + 1) & 1) * 65536 +
                        ((u64)lr * 2048 + e0 + lk * 4) * 2;
        llc_store8(dst,         hv.u);
        llc_store8(dst + 32768, lv.u);
      }
      // Ack h stores at LLC, then publish the flag (single dword).
      asm volatile("s_waitcnt vmcnt(0)" ::: "memory");
      if (lane == 0) llc_store4(flag_base + (u64)g * 4, t + 1);
      if (owner) {
        // outs consumed only by the next dispatch -> off the critical path.
        ov.h[0] = (_Float16)((hr0 * hr0 / (1.f + __expf(-hr0))) * 0.125f);
        ov.h[1] = (_Float16)((hr1 * hr1 / (1.f + __expf(-hr1))) * 0.125f);
        ov.h[2] = (_Float16)((hr2 * hr2 / (1.f + __expf(-hr2))) * 0.125f);
        ov.h[3] = (_Float16)((hr3 * hr3 / (1.f + __expf(-hr3))) * 0.125f);
        *(u64*)(outs + (size_t)(lr * 1024 + t) * 2048 + e0 + lk * 4) = ov.u;
      }
    }
    // No trailing barrier: waves re-entering the loop block at the next poll
    // barrier; red for t+1 is written only after that barrier, and wave 0
    // reaches it only after finishing its red reads for t.
  }
}

// ---------------------------------------------------------------------------
extern "C" void kernel_launch(void* const* d_in, const int* in_sizes, int n_in,
                              void* d_out, int out_size, void* d_ws, size_t ws_size,
                              hipStream_t stream)
{
  (void)in_sizes; (void)n_in; (void)out_size; (void)ws_size;
  const float* x    = (const float*)d_in[0];
  const float* h0   = (const float*)d_in[1];
  const float* Win  = (const float*)d_in[2];
  const float* Wx   = (const float*)d_in[3];
  const float* Wh   = (const float*)d_in[4];
  const float* bias = (const float*)d_in[5];
  const float* lal  = (const float*)d_in[6];
  const float* Wout = (const float*)d_in[7];

  char* ws = (char*)d_ws;
  float*    U     = (float*)(ws);                    // 67,108,864 B (fp32 u)
  _Float16* OUTS  = (_Float16*)(ws);                 // aliases U (U dead after GEMM2)
  _Float16* WoutF = (_Float16*)(ws + 67108864);      //  8,388,608 B
  _Float16* hpub  = (_Float16*)(ws + 75497472);      //    131,072 B [2][2][8][2048] f16
  int*      flags = (int*)     (ws + 75628544);      //        512 B
  float*    wxbuf = (float*)d_out;                   // wx staged in d_out

  const dim3 gg(16, 64);  // N/128, M/128

  k_convert<<<512, 256, 0, stream>>>(Wout, h0, WoutF, hpub, flags);
  // u = silu(x . W_in^T)  (split-f16, fp32 out)
  k_gemm_split<0><<<gg, 256, 0, stream>>>(x, Win, U, nullptr, 8192, 2048, 2048);
  // wx[t][b][:] = u . W_x^T + b  (split-f16, fp32 out in d_out)
  k_gemm_split<1><<<gg, 256, 0, stream>>>(U, Wx, wxbuf, bias, 8192, 2048, 2048);
  // sequential scan; writes outs/8 (f16) over the dead U region
  k_recur<<<128, 256, 0, stream>>>(Wh, wxbuf, h0, lal, OUTS, hpub, flags);
  // y = outs . W_out^T  (epilogue *8), overwrites d_out
  k_gemm_out<<<gg, 256, 0, stream>>>(OUTS, WoutF, (float*)d_out, 8192, 2048, 2048);
}